// Round 1
// baseline (137.391 us; speedup 1.0000x reference)
//
#include <hip/hip_runtime.h>
#include <math.h>

#define BB 8
#define NN 512
#define DD 512
#define DKK 64
#define NC 192  // 3*DK

// (1/sqrt(64)) * log2(e) : fold softmax scale into exp2 domain
#define T_FACT 0.18033688011112042591999058f

#if defined(__has_builtin)
#if __has_builtin(__builtin_amdgcn_exp2f)
#define EXP2F(x) __builtin_amdgcn_exp2f(x)
#else
#define EXP2F(x) exp2f(x)
#endif
#else
#define EXP2F(x) exp2f(x)
#endif

// -------------------------------------------------------------------------
// Kernel 1: QKV = X(4096x512) @ W(512x192), output stored channel-major:
// qkv_t layout [which(3)][b(8)][c(64)][n(512)] so kernel 2 reads contiguous.
// Tile 64 rows x 64 cols (blockIdx.y picks Q/K/V), K-tile 32, 4x4 micro-tile.
// -------------------------------------------------------------------------
__global__ __launch_bounds__(256) void qkv_gemm(const float* __restrict__ X,
                                                const float* __restrict__ W,
                                                float* __restrict__ qkv_t) {
    __shared__ union {
        struct {
            float As[32][68];  // A^T: As[kk][row]  (68: keep 16B align, break pow2)
            float Bs[32][68];  // Bs[kk][col]
        } s;
        float Ct[64][68];      // transpose staging for epilogue
    } sm;

    const int tid  = threadIdx.x;
    const int row0 = blockIdx.x * 64;      // 64 rows of (b,n)-flattened X
    const int which = blockIdx.y;          // 0=Q, 1=K, 2=V
    const int c0   = which * 64;
    const int tc   = tid & 15;             // micro col group
    const int tr   = tid >> 4;             // micro row group

    float acc[4][4] = {};

    for (int k0 = 0; k0 < DD; k0 += 32) {
        // stage A^T: As[kk][r] = X[row0+r][k0+kk]
        {
            const int f = tid & 7;    // which float4 along k
            const int r = tid >> 3;   // 0..31
            #pragma unroll
            for (int rr = 0; rr < 2; ++rr) {
                const int row = r + rr * 32;
                const float4 av = *(const float4*)(X + (size_t)(row0 + row) * DD + k0 + 4 * f);
                sm.s.As[4 * f + 0][row] = av.x;
                sm.s.As[4 * f + 1][row] = av.y;
                sm.s.As[4 * f + 2][row] = av.z;
                sm.s.As[4 * f + 3][row] = av.w;
            }
        }
        // stage B: Bs[kk][cc] = W[k0+kk][c0+cc]
        {
            const int cc = tid & 63;
            const int kf = tid >> 6;  // 0..3
            #pragma unroll
            for (int kk = kf; kk < 32; kk += 4)
                sm.s.Bs[kk][cc] = W[(size_t)(k0 + kk) * NC + c0 + cc];
        }
        __syncthreads();

        #pragma unroll 8
        for (int kk = 0; kk < 32; ++kk) {
            const float4 a = *(const float4*)&sm.s.As[kk][4 * tr];
            const float4 b = *(const float4*)&sm.s.Bs[kk][4 * tc];
            const float av[4] = {a.x, a.y, a.z, a.w};
            const float bv[4] = {b.x, b.y, b.z, b.w};
            #pragma unroll
            for (int i = 0; i < 4; ++i)
                #pragma unroll
                for (int j = 0; j < 4; ++j)
                    acc[i][j] = fmaf(av[i], bv[j], acc[i][j]);
        }
        __syncthreads();
    }

    // epilogue: transpose through LDS, write qkv_t[which][b][c][n] coalesced
    #pragma unroll
    for (int i = 0; i < 4; ++i)
        #pragma unroll
        for (int j = 0; j < 4; ++j)
            sm.Ct[4 * tc + j][4 * tr + i] = acc[i][j];
    __syncthreads();

    const int b  = row0 >> 9;
    const int n0 = row0 & 511;
    float* outp = qkv_t + ((size_t)which * BB * DKK + (size_t)b * DKK) * NN;
    const int fl  = tid & 15;   // float4 index within 64-wide n row
    const int cl0 = tid >> 4;   // 0..15
    #pragma unroll
    for (int cc = 0; cc < 4; ++cc) {
        const int c_l = cl0 + cc * 16;
        const float4 v = *(const float4*)&sm.Ct[c_l][4 * fl];
        *(float4*)(outp + (size_t)c_l * NN + n0 + 4 * fl) = v;
    }
}

// -------------------------------------------------------------------------
// Kernel 2: per-(b,c) rank-1 softmax attention.
// S[n,m] = q_n*k_m*scale ; A=softmax_m ; SA[n]=sum_m A[n,m] v_m
// One block per (b,c): k,v staged in LDS (broadcast reads), 2 n per thread.
// Stable max per n is t*kmax (t>0) or t*kmin (t<0), kmax/kmin block-reduced.
// -------------------------------------------------------------------------
__global__ __launch_bounds__(256) void attn(const float* __restrict__ qkv_t,
                                            float* __restrict__ sa_t) {
    __shared__ float kl[NN];
    __shared__ float vl[NN];
    __shared__ float rmax[4], rmin[4];

    const int tid = threadIdx.x;
    const int b   = blockIdx.x >> 6;
    const int c   = blockIdx.x & 63;
    const size_t chan = (size_t)(b * DKK + c) * NN;
    const float* qp = qkv_t + chan;
    const float* kp = qkv_t + (size_t)BB * DKK * NN + chan;
    const float* vp = qkv_t + (size_t)2 * BB * DKK * NN + chan;

    if (tid < 128) ((float4*)kl)[tid]       = ((const float4*)kp)[tid];
    else           ((float4*)vl)[tid - 128] = ((const float4*)vp)[tid - 128];
    __syncthreads();

    // block-wide kmax / kmin
    float mx = kl[tid], mn = mx;
    {
        const float x = kl[tid + 256];
        mx = fmaxf(mx, x);
        mn = fminf(mn, x);
    }
    #pragma unroll
    for (int off = 32; off > 0; off >>= 1) {
        mx = fmaxf(mx, __shfl_down(mx, off, 64));
        mn = fminf(mn, __shfl_down(mn, off, 64));
    }
    if ((tid & 63) == 0) { rmax[tid >> 6] = mx; rmin[tid >> 6] = mn; }
    __syncthreads();
    const float kmax = fmaxf(fmaxf(rmax[0], rmax[1]), fmaxf(rmax[2], rmax[3]));
    const float kmin = fminf(fminf(rmin[0], rmin[1]), fminf(rmin[2], rmin[3]));

    // two n-rows per thread share every LDS read of (k,v)
    const float t0 = qp[tid] * T_FACT;
    const float t1 = qp[tid + 256] * T_FACT;
    const float M0 = t0 > 0.f ? t0 * kmax : t0 * kmin;
    const float M1 = t1 > 0.f ? t1 * kmax : t1 * kmin;

    float sw0 = 0.f, sv0 = 0.f, sw1 = 0.f, sv1 = 0.f;
    const float4* k4 = (const float4*)kl;
    const float4* v4 = (const float4*)vl;
    #pragma unroll 2
    for (int j = 0; j < NN / 4; ++j) {
        const float4 kk = k4[j];
        const float4 vv = v4[j];
        const float ke[4] = {kk.x, kk.y, kk.z, kk.w};
        const float ve[4] = {vv.x, vv.y, vv.z, vv.w};
        #pragma unroll
        for (int e = 0; e < 4; ++e) {
            const float w0 = EXP2F(fmaf(t0, ke[e], -M0));
            sw0 += w0;
            sv0 = fmaf(w0, ve[e], sv0);
            const float w1 = EXP2F(fmaf(t1, ke[e], -M1));
            sw1 += w1;
            sv1 = fmaf(w1, ve[e], sv1);
        }
    }
    float* sp = sa_t + chan;
    sp[tid]       = sv0 / sw0;
    sp[tid + 256] = sv1 / sw1;
}

// -------------------------------------------------------------------------
// Kernel 3: out = SA(4096x64) @ Wo(64x512).
// sa_t is already K-major per b ([b][c][n]) -> stage full K=64 in LDS.
// Tile 64 n x 64 d, 4x4 micro-tile, float4 epilogue stores.
// -------------------------------------------------------------------------
__global__ __launch_bounds__(256) void out_gemm(const float* __restrict__ sa_t,
                                                const float* __restrict__ Wo,
                                                float* __restrict__ out) {
    __shared__ float As[64][68];  // As[c][n_local]
    __shared__ float Bs[64][68];  // Bs[c][d_local]

    const int tid  = threadIdx.x;
    const int row0 = blockIdx.x * 64;
    const int d0   = blockIdx.y * 64;
    const int b    = row0 >> 9;
    const int n0   = row0 & 511;

    const int f  = tid & 15;   // float4 index within 64
    const int r0 = tid >> 4;   // 0..15
    #pragma unroll
    for (int rr = 0; rr < 4; ++rr) {
        const int cidx = r0 + rr * 16;
        *(float4*)&As[cidx][4 * f] =
            *(const float4*)(sa_t + (size_t)(b * DKK + cidx) * NN + n0 + 4 * f);
        *(float4*)&Bs[cidx][4 * f] =
            *(const float4*)(Wo + (size_t)cidx * DD + d0 + 4 * f);
    }
    __syncthreads();

    const int tc = tid & 15;
    const int tr = tid >> 4;
    float acc[4][4] = {};
    #pragma unroll 8
    for (int k = 0; k < DKK; ++k) {
        const float4 a = *(const float4*)&As[k][4 * tr];
        const float4 bv = *(const float4*)&Bs[k][4 * tc];
        const float av[4] = {a.x, a.y, a.z, a.w};
        const float be[4] = {bv.x, bv.y, bv.z, bv.w};
        #pragma unroll
        for (int i = 0; i < 4; ++i)
            #pragma unroll
            for (int j = 0; j < 4; ++j)
                acc[i][j] = fmaf(av[i], be[j], acc[i][j]);
    }

    float* op = out + ((size_t)(b * NN + n0)) * DD + d0;
    #pragma unroll
    for (int i = 0; i < 4; ++i) {
        const float4 v = {acc[i][0], acc[i][1], acc[i][2], acc[i][3]};
        *(float4*)(op + (size_t)(4 * tr + i) * DD + 4 * tc) = v;
    }
}

extern "C" void kernel_launch(void* const* d_in, const int* in_sizes, int n_in,
                              void* d_out, int out_size, void* d_ws, size_t ws_size,
                              hipStream_t stream) {
    const float* X    = (const float*)d_in[0];  // (8,512,512)
    const float* Wqkv = (const float*)d_in[1];  // (512,192)
    const float* Wo   = (const float*)d_in[2];  // (64,512)
    float* out = (float*)d_out;                 // (8,512,512)

    float* qkv_t = (float*)d_ws;                              // 3*8*64*512 floats (3 MB)
    float* sa_t  = qkv_t + (size_t)3 * BB * DKK * NN;         // 8*64*512 floats (1 MB)

    qkv_gemm<<<dim3(64, 3), 256, 0, stream>>>(X, Wqkv, qkv_t);
    attn<<<dim3(BB * DKK), 256, 0, stream>>>(qkv_t, sa_t);
    out_gemm<<<dim3(64, 8), 256, 0, stream>>>(sa_t, Wo, out);
}

// Round 2
// 118.368 us; speedup vs baseline: 1.1607x; 1.1607x over previous
//
#include <hip/hip_runtime.h>
#include <math.h>

#define BB 8
#define NN 512
#define DD 512
#define DKK 64
#define NC 192                    // 3*DK
#define PSZ (3 * BB * DKK * NN)   // 786432 floats per full QKV image
#define CHN (BB * DKK * NN)       // 262144 floats per Q (or K or V) image

// (1/sqrt(64)) * log2(e) : fold softmax scale into exp2 domain
#define T_FACT 0.18033688011112042591999058f

#if defined(__has_builtin)
#if __has_builtin(__builtin_amdgcn_exp2f)
#define EXP2F(x) __builtin_amdgcn_exp2f(x)
#else
#define EXP2F(x) exp2f(x)
#endif
#else
#define EXP2F(x) exp2f(x)
#endif

// -------------------------------------------------------------------------
// Kernel 1: QKV = X(4096x512) @ W(512x192), channel-major output
// [which][b][c][n]. Split-K: blockIdx.z picks a K-chunk of kSteps*32;
// each z writes its own partial image (outp_base + z*PSZ). With
// grid (64,3,4), kSteps=4 -> 768 blocks = 12 waves/CU. Fallback:
// grid (64,3,1), kSteps=16 writes qkv_t directly.
// -------------------------------------------------------------------------
__global__ __launch_bounds__(256) void qkv_gemm(const float* __restrict__ X,
                                                const float* __restrict__ W,
                                                float* __restrict__ outp_base,
                                                int kSteps) {
    __shared__ union {
        struct {
            float As[32][68];  // A^T: As[kk][row]
            float Bs[32][68];  // Bs[kk][col]
        } s;
        float Ct[64][68];      // transpose staging for epilogue
    } sm;

    const int tid   = threadIdx.x;
    const int row0  = blockIdx.x * 64;   // 64 rows of (b,n)-flattened X
    const int which = blockIdx.y;        // 0=Q, 1=K, 2=V
    const int c0    = which * 64;
    const int tc    = tid & 15;
    const int tr    = tid >> 4;

    float acc[4][4] = {};

    for (int s = 0; s < kSteps; ++s) {
        const int k0 = (blockIdx.z * kSteps + s) * 32;
        // stage A^T: As[kk][r] = X[row0+r][k0+kk]
        {
            const int f = tid & 7;
            const int r = tid >> 3;
            #pragma unroll
            for (int rr = 0; rr < 2; ++rr) {
                const int row = r + rr * 32;
                const float4 av = *(const float4*)(X + (size_t)(row0 + row) * DD + k0 + 4 * f);
                sm.s.As[4 * f + 0][row] = av.x;
                sm.s.As[4 * f + 1][row] = av.y;
                sm.s.As[4 * f + 2][row] = av.z;
                sm.s.As[4 * f + 3][row] = av.w;
            }
        }
        // stage B: Bs[kk][cc] = W[k0+kk][c0+cc]
        {
            const int cc = tid & 63;
            const int kf = tid >> 6;
            #pragma unroll
            for (int kk = kf; kk < 32; kk += 4)
                sm.s.Bs[kk][cc] = W[(size_t)(k0 + kk) * NC + c0 + cc];
        }
        __syncthreads();

        #pragma unroll 8
        for (int kk = 0; kk < 32; ++kk) {
            const float4 a = *(const float4*)&sm.s.As[kk][4 * tr];
            const float4 b = *(const float4*)&sm.s.Bs[kk][4 * tc];
            const float av[4] = {a.x, a.y, a.z, a.w};
            const float bv[4] = {b.x, b.y, b.z, b.w};
            #pragma unroll
            for (int i = 0; i < 4; ++i)
                #pragma unroll
                for (int j = 0; j < 4; ++j)
                    acc[i][j] = fmaf(av[i], bv[j], acc[i][j]);
        }
        __syncthreads();
    }

    // epilogue: transpose through LDS, write [which][b][c][n] coalesced
    #pragma unroll
    for (int i = 0; i < 4; ++i)
        #pragma unroll
        for (int j = 0; j < 4; ++j)
            sm.Ct[4 * tc + j][4 * tr + i] = acc[i][j];
    __syncthreads();

    const int b  = row0 >> 9;
    const int n0 = row0 & 511;
    float* outp = outp_base + (size_t)blockIdx.z * PSZ +
                  ((size_t)which * BB * DKK + (size_t)b * DKK) * NN;
    const int fl  = tid & 15;
    const int cl0 = tid >> 4;
    #pragma unroll
    for (int cc = 0; cc < 4; ++cc) {
        const int c_l = cl0 + cc * 16;
        const float4 v = *(const float4*)&sm.Ct[c_l][4 * fl];
        *(float4*)(outp + (size_t)c_l * NN + n0 + 4 * fl) = v;
    }
}

// sum 4 split-K partials -> qkv_t. grid 768 x 256, one float4 per thread.
__global__ __launch_bounds__(256) void qkv_reduce(const float* __restrict__ p,
                                                  float* __restrict__ q) {
    const size_t i = (size_t)blockIdx.x * 256 + threadIdx.x;
    const float4* p4 = (const float4*)p;
    const float4 a = p4[i];
    const float4 b = p4[i + PSZ / 4];
    const float4 c = p4[i + 2 * (PSZ / 4)];
    const float4 d = p4[i + 3 * (PSZ / 4)];
    const float4 r = {a.x + b.x + c.x + d.x, a.y + b.y + c.y + d.y,
                      a.z + b.z + c.z + d.z, a.w + b.w + c.w + d.w};
    ((float4*)q)[i] = r;
}

// -------------------------------------------------------------------------
// Kernel 2: per-(b,c) rank-1 softmax attention.
// 1024 blocks: (channel, n-half). One n per thread; k,v staged in LDS
// (same-address broadcast reads). Stable max via block-reduced kmax/kmin.
// -------------------------------------------------------------------------
__global__ __launch_bounds__(256) void attn(const float* __restrict__ qkv_t,
                                            float* __restrict__ sa_t) {
    __shared__ float kl[NN];
    __shared__ float vl[NN];
    __shared__ float rmax[4], rmin[4];

    const int tid  = threadIdx.x;
    const int bc   = blockIdx.x >> 1;
    const int half = blockIdx.x & 1;
    const size_t chan = (size_t)bc * NN;
    const float* qp = qkv_t + chan;
    const float* kp = qkv_t + (size_t)CHN + chan;
    const float* vp = qkv_t + (size_t)2 * CHN + chan;

    if (tid < 128) ((float4*)kl)[tid]       = ((const float4*)kp)[tid];
    else           ((float4*)vl)[tid - 128] = ((const float4*)vp)[tid - 128];
    __syncthreads();

    float mx = fmaxf(kl[tid], kl[tid + 256]);
    float mn = fminf(kl[tid], kl[tid + 256]);
    #pragma unroll
    for (int off = 32; off > 0; off >>= 1) {
        mx = fmaxf(mx, __shfl_down(mx, off, 64));
        mn = fminf(mn, __shfl_down(mn, off, 64));
    }
    if ((tid & 63) == 0) { rmax[tid >> 6] = mx; rmin[tid >> 6] = mn; }
    __syncthreads();
    const float kmax = fmaxf(fmaxf(rmax[0], rmax[1]), fmaxf(rmax[2], rmax[3]));
    const float kmin = fminf(fminf(rmin[0], rmin[1]), fminf(rmin[2], rmin[3]));

    const int n = half * 256 + tid;
    const float t = qp[n] * T_FACT;
    const float M = t > 0.f ? t * kmax : t * kmin;

    float sw = 0.f, sv = 0.f;
    const float4* k4 = (const float4*)kl;
    const float4* v4 = (const float4*)vl;
    #pragma unroll 4
    for (int j = 0; j < NN / 4; ++j) {
        const float4 kk = k4[j];
        const float4 vv = v4[j];
        const float ke[4] = {kk.x, kk.y, kk.z, kk.w};
        const float ve[4] = {vv.x, vv.y, vv.z, vv.w};
        #pragma unroll
        for (int e = 0; e < 4; ++e) {
            const float w = EXP2F(fmaf(t, ke[e], -M));
            sw += w;
            sv = fmaf(w, ve[e], sv);
        }
    }
    sa_t[chan + n] = sv / sw;
}

// -------------------------------------------------------------------------
// Kernel 3: out = SA(4096x64) @ Wo(64x512). sa_t is K-major per b.
// 512 threads/block (8 waves), 64x64 tile, 2x4 micro-tile.
// -------------------------------------------------------------------------
__global__ __launch_bounds__(512) void out_gemm(const float* __restrict__ sa_t,
                                                const float* __restrict__ Wo,
                                                float* __restrict__ out) {
    __shared__ float As[64][68];  // As[c][n_local]
    __shared__ float Bs[64][68];  // Bs[c][d_local]

    const int tid  = threadIdx.x;
    const int row0 = blockIdx.x * 64;
    const int d0   = blockIdx.y * 64;
    const int b    = row0 >> 9;
    const int n0   = row0 & 511;

    // stage: 1024 float4 slots, 2 per thread
    #pragma unroll
    for (int ss = 0; ss < 2; ++ss) {
        const int s = tid + ss * 512;
        const int cidx = s >> 4;
        const int f    = s & 15;
        *(float4*)&As[cidx][4 * f] =
            *(const float4*)(sa_t + (size_t)(b * DKK + cidx) * NN + n0 + 4 * f);
        *(float4*)&Bs[cidx][4 * f] =
            *(const float4*)(Wo + (size_t)cidx * DD + d0 + 4 * f);
    }
    __syncthreads();

    const int tc = tid & 15;   // 4 cols
    const int tr = tid >> 4;   // 0..31 -> 2 rows
    float acc[2][4] = {};
    #pragma unroll 8
    for (int k = 0; k < DKK; ++k) {
        const float2 a = *(const float2*)&As[k][2 * tr];
        const float4 bv = *(const float4*)&Bs[k][4 * tc];
        const float av[2] = {a.x, a.y};
        const float be[4] = {bv.x, bv.y, bv.z, bv.w};
        #pragma unroll
        for (int i = 0; i < 2; ++i)
            #pragma unroll
            for (int j = 0; j < 4; ++j)
                acc[i][j] = fmaf(av[i], be[j], acc[i][j]);
    }

    float* op = out + ((size_t)(b * NN + n0)) * DD + d0;
    #pragma unroll
    for (int i = 0; i < 2; ++i) {
        const float4 v = {acc[i][0], acc[i][1], acc[i][2], acc[i][3]};
        *(float4*)(op + (size_t)(2 * tr + i) * DD + 4 * tc) = v;
    }
}

extern "C" void kernel_launch(void* const* d_in, const int* in_sizes, int n_in,
                              void* d_out, int out_size, void* d_ws, size_t ws_size,
                              hipStream_t stream) {
    const float* X    = (const float*)d_in[0];  // (8,512,512)
    const float* Wqkv = (const float*)d_in[1];  // (512,192)
    const float* Wo   = (const float*)d_in[2];  // (64,512)
    float* out = (float*)d_out;                 // (8,512,512)

    const size_t need_split = (size_t)(4 * PSZ + PSZ + CHN) * sizeof(float); // 16 MB
    float* qkv_t;
    float* sa_t;

    if (ws_size >= need_split) {
        float* partial = (float*)d_ws;
        qkv_t = partial + (size_t)4 * PSZ;
        sa_t  = qkv_t + PSZ;
        qkv_gemm<<<dim3(64, 3, 4), 256, 0, stream>>>(X, Wqkv, partial, 4);
        qkv_reduce<<<dim3(PSZ / 4 / 256), 256, 0, stream>>>(partial, qkv_t);
    } else {
        qkv_t = (float*)d_ws;
        sa_t  = qkv_t + PSZ;
        qkv_gemm<<<dim3(64, 3, 1), 256, 0, stream>>>(X, Wqkv, qkv_t, 16);
    }

    attn<<<dim3(2 * BB * DKK), 256, 0, stream>>>(qkv_t, sa_t);
    out_gemm<<<dim3(64, 8), 512, 0, stream>>>(sa_t, Wo, out);
}